// Round 4
// baseline (562.183 us; speedup 1.0000x reference)
//
#include <hip/hip_runtime.h>
#include <hip/hip_bf16.h>

// Problem constants
static constexpr int BB = 2;      // batch
static constexpr int SS = 2048;   // seq len
static constexpr int DD = 2048;   // model dim
static constexpr int HH = 16;     // heads
static constexpr int HD = 128;    // head dim

typedef __bf16 bf16_t;
typedef __bf16 bf16x8 __attribute__((ext_vector_type(8)));
typedef __bf16 bf16x4 __attribute__((ext_vector_type(4)));
typedef float  floatx4 __attribute__((ext_vector_type(4)));

// Async global->LDS, 16B per lane. LDS dest is wave-uniform base + lane*16.
__device__ __forceinline__ void gl2lds16(const bf16_t* g, bf16_t* l) {
    __builtin_amdgcn_global_load_lds(
        (const __attribute__((address_space(1))) void*)g,
        (__attribute__((address_space(3))) void*)l, 16, 0, 0);
}

// ---------------------------------------------------------------------------
// Cast x (fp32) -> bf16, vectorized 4 elements/thread
// ---------------------------------------------------------------------------
__global__ void cast_x_kernel(const float* __restrict__ x, bf16_t* __restrict__ xb) {
    int i = blockIdx.x * 256 + threadIdx.x;
    float4 v = ((const float4*)x)[i];
    bf16x4 o;
    o.x = (bf16_t)v.x; o.y = (bf16_t)v.y; o.z = (bf16_t)v.z; o.w = (bf16_t)v.w;
    ((bf16x4*)xb)[i] = o;
}

// ---------------------------------------------------------------------------
// Transpose + cast one DxD fp32 weight into bf16 W^T (row n holds W[:,n])
// block (32,8), grid (D/32, D/32)
// ---------------------------------------------------------------------------
__global__ void transpose_cast_kernel(const float* __restrict__ W, bf16_t* __restrict__ Wt) {
    __shared__ float tile[32][33];
    int bx = blockIdx.x * 32;   // n
    int by = blockIdx.y * 32;   // k
    int tx = threadIdx.x, ty = threadIdx.y;
#pragma unroll
    for (int j = 0; j < 4; ++j)
        tile[ty + j * 8][tx] = W[(size_t)(by + ty + j * 8) * DD + bx + tx];
    __syncthreads();
#pragma unroll
    for (int j = 0; j < 4; ++j)
        Wt[(size_t)(bx + ty + j * 8) * DD + by + tx] = (bf16_t)tile[tx][ty + j * 8];
}

// ---------------------------------------------------------------------------
// bf16 GEMM, C[M x N] = A[M x K] @ Bt[N x K]^T.  128x128 tile, 256 threads,
// m97 structure: unpadded 128x64 LDS tiles staged via global_load_lds w=16,
// XOR chunk swizzle so ds_read_b128 hits the 8-beat minimum.
// MODE 0: QKV epilogue -> scatter bf16 Q[b][h][s][d], K[b][h][s][d], Vt[b][h][d][s]
// MODE 1: plain fp32 epilogue -> Cf[m*N+n]
// ---------------------------------------------------------------------------
template <int MODE>
__global__ __launch_bounds__(256, 2) void gemm_bt_kernel(
    const bf16_t* __restrict__ A, const bf16_t* __restrict__ Bt,
    float* __restrict__ Cf, bf16_t* __restrict__ Qw, bf16_t* __restrict__ Kw,
    bf16_t* __restrict__ Vtw, int N, int K) {
    __shared__ __align__(16) bf16_t As[128 * 64];
    __shared__ __align__(16) bf16_t Bs[128 * 64];

    const int t = threadIdx.x;
    const int lane = t & 63;
    const int wave = t >> 6;
    const int lrow = lane & 15;   // m (A) / n (B) within 16
    const int lkq  = lane >> 4;   // k-quad
    const int wm = (wave & 1) * 64;
    const int wn = (wave >> 1) * 64;
    const int m0 = blockIdx.y * 128;
    const int n0 = blockIdx.x * 128;

    floatx4 acc[4][4];
#pragma unroll
    for (int i = 0; i < 4; ++i)
#pragma unroll
        for (int j = 0; j < 4; ++j) acc[i][j] = (floatx4)0.0f;

    // staging geometry: per instr a wave moves 8 rows x 64 cols (1024B).
    const int srow  = lane >> 3;                    // row within 8
    const int sch   = (lane & 7) ^ srow;            // swizzled global chunk

    for (int k0 = 0; k0 < K; k0 += 64) {
        __syncthreads();
#pragma unroll
        for (int p = 0; p < 4; ++p) {
            int r = wave * 32 + p * 8 + srow;
            gl2lds16(A  + (size_t)(m0 + r) * K + k0 + sch * 8, As + (wave * 32 + p * 8) * 64);
            gl2lds16(Bt + (size_t)(n0 + r) * K + k0 + sch * 8, Bs + (wave * 32 + p * 8) * 64);
        }
        __syncthreads();
#pragma unroll
        for (int ks = 0; ks < 2; ++ks) {
            bf16x8 af[4], bg[4];
#pragma unroll
            for (int i = 0; i < 4; ++i) {
                int pos = ((ks * 4 + lkq) ^ (lrow & 7)) * 8;
                af[i] = *(const bf16x8*)(As + (wm + i * 16 + lrow) * 64 + pos);
                bg[i] = *(const bf16x8*)(Bs + (wn + i * 16 + lrow) * 64 + pos);
            }
#pragma unroll
            for (int i = 0; i < 4; ++i)
#pragma unroll
                for (int j = 0; j < 4; ++j)
                    acc[i][j] = __builtin_amdgcn_mfma_f32_16x16x32_bf16(af[i], bg[j], acc[i][j], 0, 0, 0);
        }
    }

    // Epilogue. C/D layout (verified m89): col = lane&15, row = (lane>>4)*4 + reg.
#pragma unroll
    for (int i = 0; i < 4; ++i)
#pragma unroll
        for (int j = 0; j < 4; ++j)
#pragma unroll
            for (int r = 0; r < 4; ++r) {
                int m = m0 + wm + i * 16 + lkq * 4 + r;
                int n = n0 + wn + j * 16 + lrow;
                float v = acc[i][j][r];
                if (MODE == 1) {
                    Cf[(size_t)m * N + n] = v;
                } else {
                    bf16_t bv = (bf16_t)v;
                    int b = m >> 11, s = m & (SS - 1);
                    if (n < DD) {
                        int h = n >> 7, d = n & 127;
                        Qw[(((size_t)b * HH + h) * SS + s) * HD + d] = bv;
                    } else if (n < 2 * DD) {
                        int nn = n - DD;
                        int h = nn >> 7, d = nn & 127;
                        Kw[(((size_t)b * HH + h) * SS + s) * HD + d] = bv;
                    } else {
                        int nn = n - 2 * DD;
                        int h = nn >> 7, d = nn & 127;
                        Vtw[(((size_t)b * HH + h) * HD + d) * SS + s] = bv;
                    }
                }
            }
}

// ---------------------------------------------------------------------------
// In-place interleaved RoPE on Q and K, layout [b][h][s][d], fp32 math.
// ---------------------------------------------------------------------------
__global__ void rope_kernel(bf16_t* __restrict__ Qw, bf16_t* __restrict__ Kw) {
    int idx = blockIdx.x * 256 + threadIdx.x;   // < BB*HH*SS*64
    int i  = idx & 63;
    int s  = (idx >> 6) & (SS - 1);
    int bh = idx >> 17;
    float inv = expf(-(float)(2 * i) * (9.210340371976184f / 128.0f));
    float ang = (float)s * inv;
    float c = cosf(ang), sn = sinf(ang);
    size_t base = ((size_t)bh * SS + s) * HD + 2 * i;
    float q1 = (float)Qw[base], q2 = (float)Qw[base + 1];
    Qw[base]     = (bf16_t)(q1 * c - q2 * sn);
    Qw[base + 1] = (bf16_t)(q1 * sn + q2 * c);
    float k1 = (float)Kw[base], k2 = (float)Kw[base + 1];
    Kw[base]     = (bf16_t)(k1 * c - k2 * sn);
    Kw[base + 1] = (bf16_t)(k1 * sn + k2 * c);
}

// ---------------------------------------------------------------------------
// Causal flash attention, S^T formulation, BARRIER-FREE.
// 128-q tile / block, 4 waves; wave owns 2 q-sets of 16 rows
// (qb = q0 + qs*64 + wave*16). K/V MFMA fragments are loaded DIRECTLY from
// global into VGPRs (16 rows x 64B contiguous per instr) -- no LDS staging,
// no __syncthreads, no vmcnt(0) drain. kf shared across both q-sets; vf loads
// issued before softmax so their latency hides under the exp2/reduce VALU.
// Only LDS use: per-wave Ps buffer for the P C->A layout transform
// (lgkmcnt-only, no barrier). Ballot-gated O-rescale skips the 64 v_mul
// when no lane's running max moved (exact: exp2f(0)==1).
// ---------------------------------------------------------------------------
__global__ __launch_bounds__(256, 2) void flash_attn_kernel(
    const bf16_t* __restrict__ Qw, const bf16_t* __restrict__ Kw,
    const bf16_t* __restrict__ Vtw, bf16_t* __restrict__ Attn) {
    __shared__ __align__(16) bf16_t Ps[4][16 * 72];  // per wave [q][k], +8 pad

    const int t = threadIdx.x;
    const int lane = t & 63;
    const int wave = t >> 6;
    const int lrow = lane & 15;
    const int lkq  = lane >> 4;
    const int bx = blockIdx.x;
    const int qtile = (bx & 1) ? (bx >> 1) : (15 - (bx >> 1));   // longest first
    const int bh = blockIdx.y;
    const int q0 = qtile * 128;

    const bf16_t* Qbh = Qw + (size_t)bh * SS * HD;
    const bf16_t* Kbh = Kw + (size_t)bh * SS * HD;
    const bf16_t* Vbh = Vtw + (size_t)bh * HD * SS;

    const int qb[2] = { q0 + wave * 16, q0 + 64 + wave * 16 };

    // Q fragments (B-operand layout: n=lane&15=q, k=quad*8+j), scale*log2e folded
    const float qscale = 0.08838834764831845f * 1.4426950408889634f;
    bf16x8 qf[2][4];
#pragma unroll
    for (int qs = 0; qs < 2; ++qs)
#pragma unroll
        for (int kc4 = 0; kc4 < 4; ++kc4) {
            qf[qs][kc4] = *(const bf16x8*)(Qbh + (size_t)(qb[qs] + lrow) * HD + kc4 * 32 + lkq * 8);
#pragma unroll
            for (int e = 0; e < 8; ++e) qf[qs][kc4][e] = (bf16_t)((float)qf[qs][kc4][e] * qscale);
        }

    floatx4 oacc[2][8];
#pragma unroll
    for (int qs = 0; qs < 2; ++qs)
#pragma unroll
        for (int i = 0; i < 8; ++i) oacc[qs][i] = (floatx4)0.0f;
    float m_i[2] = { -1e30f, -1e30f };
    float l_i[2] = { 0.0f, 0.0f };

    const int nch = 2 * qtile + 2;
    for (int kc = 0; kc < nch; ++kc) {
        // K fragments (A-operand: m=lane&15 -> k-row, k-col = kc4*32+lkq*8+j):
        // each load = 16 rows x 64B contiguous from global.
        bf16x8 kf[4][4];
#pragma unroll
        for (int nf = 0; nf < 4; ++nf)
#pragma unroll
            for (int kc4 = 0; kc4 < 4; ++kc4)
                kf[nf][kc4] = *(const bf16x8*)(Kbh + (size_t)(kc * 64 + nf * 16 + lrow) * HD +
                                               kc4 * 32 + lkq * 8);

        const bool act0 = (kc * 64 <= qb[0] + 15);   // qs=1 is active for all kc<nch

        // S^T[64k x 16q] for both q-sets from shared kf
        floatx4 sacc[2][4];
#pragma unroll
        for (int qs = 0; qs < 2; ++qs)
#pragma unroll
            for (int i = 0; i < 4; ++i) sacc[qs][i] = (floatx4)0.0f;
#pragma unroll
        for (int nf = 0; nf < 4; ++nf)
#pragma unroll
            for (int kc4 = 0; kc4 < 4; ++kc4) {
                if (act0)
                    sacc[0][nf] = __builtin_amdgcn_mfma_f32_16x16x32_bf16(kf[nf][kc4], qf[0][kc4], sacc[0][nf], 0, 0, 0);
                sacc[1][nf] = __builtin_amdgcn_mfma_f32_16x16x32_bf16(kf[nf][kc4], qf[1][kc4], sacc[1][nf], 0, 0, 0);
            }

        // V fragments (B-operand: n=lane&15 -> d, k = k2*32+lkq*8+j along s):
        // issued now so the ~200cyc latency hides under the softmax VALU below.
        bf16x8 vf[8][2];
#pragma unroll
        for (int nf8 = 0; nf8 < 8; ++nf8)
#pragma unroll
            for (int k2 = 0; k2 < 2; ++k2)
                vf[nf8][k2] = *(const bf16x8*)(Vbh + (size_t)(nf8 * 16 + lrow) * SS +
                                               kc * 64 + k2 * 32 + lkq * 8);

#pragma unroll
        for (int qs = 0; qs < 2; ++qs) {
            const int qbase = qb[qs];                 // wave-uniform
            if (qs == 0 && !act0) continue;           // q-set fully masked: skip

            const int qg = qbase + lrow;
            float mx = m_i[qs];
            if (kc * 64 + 63 > qbase) {
                // diagonal chunk: causal mask + max
#pragma unroll
                for (int nf = 0; nf < 4; ++nf)
#pragma unroll
                    for (int r = 0; r < 4; ++r) {
                        int kg = kc * 64 + nf * 16 + lkq * 4 + r;
                        float sv = (kg > qg) ? -1e30f : sacc[qs][nf][r];
                        sacc[qs][nf][r] = sv;
                        mx = fmaxf(mx, sv);
                    }
            } else {
#pragma unroll
                for (int nf = 0; nf < 4; ++nf)
#pragma unroll
                    for (int r = 0; r < 4; ++r) mx = fmaxf(mx, sacc[qs][nf][r]);
            }
            mx = fmaxf(mx, __shfl_xor(mx, 16));
            mx = fmaxf(mx, __shfl_xor(mx, 32));
            float alpha = exp2f(m_i[qs] - mx);
            m_i[qs] = mx;

            float rs = 0.0f;
#pragma unroll
            for (int nf = 0; nf < 4; ++nf)
#pragma unroll
                for (int r = 0; r < 4; ++r) {
                    float pv = exp2f(sacc[qs][nf][r] - mx);
                    sacc[qs][nf][r] = pv;
                    rs += pv;
                }
            rs += __shfl_xor(rs, 16);
            rs += __shfl_xor(rs, 32);
            l_i[qs] = l_i[qs] * alpha + rs;

            // rescale O only if some lane's max moved (alpha<1); wave-uniform
            if (__ballot(alpha < 1.0f)) {
                float av[4];
#pragma unroll
                for (int r = 0; r < 4; ++r) av[r] = __shfl(alpha, lkq * 4 + r);
#pragma unroll
                for (int nf8 = 0; nf8 < 8; ++nf8)
#pragma unroll
                    for (int r = 0; r < 4; ++r) oacc[qs][nf8][r] *= av[r];
            }

            // P store: 4 consecutive k per (nf) -> ds_write_b64 (per-wave, no barrier)
#pragma unroll
            for (int nf = 0; nf < 4; ++nf) {
                bf16x4 pk;
#pragma unroll
                for (int r = 0; r < 4; ++r) pk[r] = (bf16_t)sacc[qs][nf][r];
                *(bf16x4*)(Ps[wave] + lrow * 72 + nf * 16 + lkq * 4) = pk;
            }

            // PV: O[16q x 128d] += P[16 x 64] @ V[64 x 128]
            bf16x8 pa[2];
#pragma unroll
            for (int k2 = 0; k2 < 2; ++k2)
                pa[k2] = *(const bf16x8*)(Ps[wave] + lrow * 72 + k2 * 32 + lkq * 8);
#pragma unroll
            for (int nf8 = 0; nf8 < 8; ++nf8)
#pragma unroll
                for (int k2 = 0; k2 < 2; ++k2)
                    oacc[qs][nf8] = __builtin_amdgcn_mfma_f32_16x16x32_bf16(pa[k2], vf[nf8][k2], oacc[qs][nf8], 0, 0, 0);
        }
    }

    // finalize: O /= l, write attn[b][s][h*128+d] (bf16)
    int bb = bh >> 4, h = bh & 15;
#pragma unroll
    for (int qs = 0; qs < 2; ++qs)
#pragma unroll
        for (int r = 0; r < 4; ++r) {
            float invl = 1.0f / __shfl(l_i[qs], lkq * 4 + r);
            int q = qb[qs] + lkq * 4 + r;
#pragma unroll
            for (int nf8 = 0; nf8 < 8; ++nf8)
                Attn[((size_t)bb * SS + q) * DD + h * HD + nf8 * 16 + lrow] =
                    (bf16_t)(oacc[qs][nf8][r] * invl);
        }
}

// ---------------------------------------------------------------------------
extern "C" void kernel_launch(void* const* d_in, const int* in_sizes, int n_in,
                              void* d_out, int out_size, void* d_ws, size_t ws_size,
                              hipStream_t stream) {
    const float* x  = (const float*)d_in[0];
    const float* Wq = (const float*)d_in[1];
    const float* Wk = (const float*)d_in[2];
    const float* Wv = (const float*)d_in[3];
    const float* Wo = (const float*)d_in[4];
    float* out = (float*)d_out;

    bf16_t* p = (bf16_t*)d_ws;
    bf16_t* Xb    = p; p += (size_t)BB * SS * DD;
    bf16_t* Wqkvt = p; p += (size_t)3 * DD * DD;
    bf16_t* Wot   = p; p += (size_t)DD * DD;
    bf16_t* Qw    = p; p += (size_t)BB * HH * SS * HD;
    bf16_t* Kw    = p; p += (size_t)BB * HH * SS * HD;
    bf16_t* Vtw   = p; p += (size_t)BB * HH * SS * HD;
    bf16_t* Attn  = p; p += (size_t)BB * SS * DD;

    cast_x_kernel<<<(BB * SS * DD / 4) / 256, 256, 0, stream>>>(x, Xb);

    dim3 tb(32, 8), tg(DD / 32, DD / 32);
    transpose_cast_kernel<<<tg, tb, 0, stream>>>(Wq, Wqkvt);
    transpose_cast_kernel<<<tg, tb, 0, stream>>>(Wk, Wqkvt + (size_t)DD * DD);
    transpose_cast_kernel<<<tg, tb, 0, stream>>>(Wv, Wqkvt + (size_t)2 * DD * DD);
    transpose_cast_kernel<<<tg, tb, 0, stream>>>(Wo, Wot);

    // QKV: [4096 x 2048] @ [2048 x 6144] -> Q/K/Vt scatter
    gemm_bt_kernel<0><<<dim3(3 * DD / 128, BB * SS / 128), 256, 0, stream>>>(
        Xb, Wqkvt, nullptr, Qw, Kw, Vtw, 3 * DD, DD);

    rope_kernel<<<(BB * HH * SS * 64) / 256, 256, 0, stream>>>(Qw, Kw);

    flash_attn_kernel<<<dim3(SS / 128, BB * HH), 256, 0, stream>>>(Qw, Kw, Vtw, Attn);

    // out = attn @ Wo : [4096 x 2048] @ [2048 x 2048] -> fp32
    gemm_bt_kernel<1><<<dim3(DD / 128, BB * SS / 128), 256, 0, stream>>>(
        Attn, Wot, out, nullptr, nullptr, nullptr, DD, DD);
}

// Round 6
// 411.005 us; speedup vs baseline: 1.3678x; 1.3678x over previous
//
#include <hip/hip_runtime.h>
#include <hip/hip_bf16.h>

// Problem constants
static constexpr int BB = 2;      // batch
static constexpr int SS = 2048;   // seq len
static constexpr int DD = 2048;   // model dim
static constexpr int HH = 16;     // heads
static constexpr int HD = 128;    // head dim

typedef __bf16 bf16_t;
typedef __bf16 bf16x8 __attribute__((ext_vector_type(8)));
typedef __bf16 bf16x4 __attribute__((ext_vector_type(4)));
typedef float  floatx4 __attribute__((ext_vector_type(4)));

// Async global->LDS, 16B per lane. LDS dest is wave-uniform base + lane*16.
__device__ __forceinline__ void gl2lds16(const bf16_t* g, bf16_t* l) {
    __builtin_amdgcn_global_load_lds(
        (const __attribute__((address_space(1))) void*)g,
        (__attribute__((address_space(3))) void*)l, 16, 0, 0);
}

// ---------------------------------------------------------------------------
// Cast x (fp32) -> bf16, vectorized 4 elements/thread
// ---------------------------------------------------------------------------
__global__ void cast_x_kernel(const float* __restrict__ x, bf16_t* __restrict__ xb) {
    int i = blockIdx.x * 256 + threadIdx.x;
    float4 v = ((const float4*)x)[i];
    bf16x4 o;
    o.x = (bf16_t)v.x; o.y = (bf16_t)v.y; o.z = (bf16_t)v.z; o.w = (bf16_t)v.w;
    ((bf16x4*)xb)[i] = o;
}

// ---------------------------------------------------------------------------
// Transpose + cast one DxD fp32 weight into bf16 W^T (row n holds W[:,n])
// block (32,8), grid (D/32, D/32)
// ---------------------------------------------------------------------------
__global__ void transpose_cast_kernel(const float* __restrict__ W, bf16_t* __restrict__ Wt) {
    __shared__ float tile[32][33];
    int bx = blockIdx.x * 32;   // n
    int by = blockIdx.y * 32;   // k
    int tx = threadIdx.x, ty = threadIdx.y;
#pragma unroll
    for (int j = 0; j < 4; ++j)
        tile[ty + j * 8][tx] = W[(size_t)(by + ty + j * 8) * DD + bx + tx];
    __syncthreads();
#pragma unroll
    for (int j = 0; j < 4; ++j)
        Wt[(size_t)(bx + ty + j * 8) * DD + by + tx] = (bf16_t)tile[tx][ty + j * 8];
}

// ---------------------------------------------------------------------------
// bf16 GEMM, C[M x N] = A[M x K] @ Bt[N x K]^T.  128x128 tile, 256 threads,
// m97 structure: unpadded 128x64 LDS tiles staged via global_load_lds w=16,
// XOR chunk swizzle so ds_read_b128 hits the 8-beat minimum.
// MODE 0: QKV epilogue -> scatter bf16 Q[b][h][s][d], K[b][h][s][d],
//         V[b][h][s][d] (natural layout; transposed later by vtrans_kernel)
// MODE 1: plain fp32 epilogue -> Cf[m*N+n]
// ---------------------------------------------------------------------------
template <int MODE>
__global__ __launch_bounds__(256, 2) void gemm_bt_kernel(
    const bf16_t* __restrict__ A, const bf16_t* __restrict__ Bt,
    float* __restrict__ Cf, bf16_t* __restrict__ Qw, bf16_t* __restrict__ Kw,
    bf16_t* __restrict__ Vw, int N, int K) {
    __shared__ __align__(16) bf16_t As[128 * 64];
    __shared__ __align__(16) bf16_t Bs[128 * 64];

    const int t = threadIdx.x;
    const int lane = t & 63;
    const int wave = t >> 6;
    const int lrow = lane & 15;   // m (A) / n (B) within 16
    const int lkq  = lane >> 4;   // k-quad
    const int wm = (wave & 1) * 64;
    const int wn = (wave >> 1) * 64;
    const int m0 = blockIdx.y * 128;
    const int n0 = blockIdx.x * 128;

    floatx4 acc[4][4];
#pragma unroll
    for (int i = 0; i < 4; ++i)
#pragma unroll
        for (int j = 0; j < 4; ++j) acc[i][j] = (floatx4)0.0f;

    // staging geometry: per instr a wave moves 8 rows x 64 cols (1024B).
    const int srow  = lane >> 3;                    // row within 8
    const int sch   = (lane & 7) ^ srow;            // swizzled global chunk

    for (int k0 = 0; k0 < K; k0 += 64) {
        __syncthreads();
#pragma unroll
        for (int p = 0; p < 4; ++p) {
            int r = wave * 32 + p * 8 + srow;
            gl2lds16(A  + (size_t)(m0 + r) * K + k0 + sch * 8, As + (wave * 32 + p * 8) * 64);
            gl2lds16(Bt + (size_t)(n0 + r) * K + k0 + sch * 8, Bs + (wave * 32 + p * 8) * 64);
        }
        __syncthreads();
#pragma unroll
        for (int ks = 0; ks < 2; ++ks) {
            bf16x8 af[4], bg[4];
#pragma unroll
            for (int i = 0; i < 4; ++i) {
                int pos = ((ks * 4 + lkq) ^ (lrow & 7)) * 8;
                af[i] = *(const bf16x8*)(As + (wm + i * 16 + lrow) * 64 + pos);
                bg[i] = *(const bf16x8*)(Bs + (wn + i * 16 + lrow) * 64 + pos);
            }
#pragma unroll
            for (int i = 0; i < 4; ++i)
#pragma unroll
                for (int j = 0; j < 4; ++j)
                    acc[i][j] = __builtin_amdgcn_mfma_f32_16x16x32_bf16(af[i], bg[j], acc[i][j], 0, 0, 0);
        }
    }

    // Epilogue. C/D layout (verified m89): col = lane&15, row = (lane>>4)*4 + reg.
#pragma unroll
    for (int i = 0; i < 4; ++i)
#pragma unroll
        for (int j = 0; j < 4; ++j)
#pragma unroll
            for (int r = 0; r < 4; ++r) {
                int m = m0 + wm + i * 16 + lkq * 4 + r;
                int n = n0 + wn + j * 16 + lrow;
                float v = acc[i][j][r];
                if (MODE == 1) {
                    Cf[(size_t)m * N + n] = v;
                } else {
                    bf16_t bv = (bf16_t)v;
                    int b = m >> 11, s = m & (SS - 1);
                    int nn = n & (DD - 1);
                    int h = nn >> 7, d = nn & 127;
                    size_t off = (((size_t)b * HH + h) * SS + s) * HD + d;
                    if (n < DD)            Qw[off] = bv;
                    else if (n < 2 * DD)   Kw[off] = bv;
                    else                   Vw[off] = bv;
                }
            }
}

// ---------------------------------------------------------------------------
// In-place interleaved RoPE on Q and K, layout [b][h][s][d], fp32 math.
// ---------------------------------------------------------------------------
__global__ void rope_kernel(bf16_t* __restrict__ Qw, bf16_t* __restrict__ Kw) {
    int idx = blockIdx.x * 256 + threadIdx.x;   // < BB*HH*SS*64
    int i  = idx & 63;
    int s  = (idx >> 6) & (SS - 1);
    int bh = idx >> 17;
    float inv = expf(-(float)(2 * i) * (9.210340371976184f / 128.0f));
    float ang = (float)s * inv;
    float c = cosf(ang), sn = sinf(ang);
    size_t base = ((size_t)bh * SS + s) * HD + 2 * i;
    float q1 = (float)Qw[base], q2 = (float)Qw[base + 1];
    Qw[base]     = (bf16_t)(q1 * c - q2 * sn);
    Qw[base + 1] = (bf16_t)(q1 * sn + q2 * c);
    float k1 = (float)Kw[base], k2 = (float)Kw[base + 1];
    Kw[base]     = (bf16_t)(k1 * c - k2 * sn);
    Kw[base + 1] = (bf16_t)(k1 * sn + k2 * c);
}

// ---------------------------------------------------------------------------
// V transpose: Vw [bh][s][d] -> Vt [bh][d][s]. 64x64 tiles via LDS (pad 65),
// coalesced 16B+ on both global sides.
// grid (SS/64, HD/64, BB*HH), block 256.
// Read side: 2 passes x 256 thr x 8 elems = 4096 = 64x64.
// Write side: ONE pass of 256 thr x 16 elems = 4096 (d in [0,64) -- the
// round-5 bug was a second pass pushing d to 127, OOB on lds[64][] and
// stomping the neighboring d-block in Vt).
// ---------------------------------------------------------------------------
__global__ void vtrans_kernel(const bf16_t* __restrict__ Vw, bf16_t* __restrict__ Vt) {
    __shared__ unsigned short lds[64][65];
    const int t = threadIdx.x;
    const int s0 = blockIdx.x * 64, d0 = blockIdx.y * 64, bh = blockIdx.z;
    const bf16_t* src = Vw + ((size_t)bh * SS + s0) * HD + d0;
    bf16_t* dst = Vt + ((size_t)bh * HD + d0) * SS + s0;
#pragma unroll
    for (int p = 0; p < 2; ++p) {
        int c = p * 256 + t;
        int s = c >> 3, ch = c & 7;                  // 8 chunks of 16B per 64-d row
        uint4 v = *(const uint4*)(src + (size_t)s * HD + ch * 8);
        const unsigned short* pv = (const unsigned short*)&v;
#pragma unroll
        for (int e = 0; e < 8; ++e) lds[ch * 8 + e][s] = pv[e];
    }
    __syncthreads();
    {
        int d = t >> 2, sb = (t & 3) * 16;           // 16 s-elements = 32B per thread
        uint4 o[2];
        unsigned short* po = (unsigned short*)o;
#pragma unroll
        for (int e = 0; e < 16; ++e) po[e] = lds[d][sb + e];
        *(uint4*)(dst + (size_t)d * SS + sb) = o[0];
        *(uint4*)(dst + (size_t)d * SS + sb + 8) = o[1];
    }
}

// ---------------------------------------------------------------------------
// Causal flash attention, S^T formulation, 128-q tile, FRAGMENT-REUSE version.
// Round-2 staged structure (best measured) + each kf/vf LDS read feeds BOTH
// q-sets' MFMAs -> LDS bytes per MFMA halved (1.125KB -> 0.56KB), which was
// the measured ceiling (MfmaUtil ~10% == LDS-BW bound at 85 B/cyc/CU).
// 4 waves; wave owns 2 q-sets of 16 rows (qb = q0 + qs*64 + wave*16).
// ---------------------------------------------------------------------------
__global__ __launch_bounds__(256, 2) void flash_attn_kernel(
    const bf16_t* __restrict__ Qw, const bf16_t* __restrict__ Kw,
    const bf16_t* __restrict__ Vtw, bf16_t* __restrict__ Attn) {
    __shared__ __align__(16) bf16_t Ks[64 * 128];    // [k][d], chunks swizzled
    __shared__ __align__(16) bf16_t Vs[128 * 64];    // [d][s], chunks swizzled
    __shared__ __align__(16) bf16_t Ps[4][16 * 72];  // per wave [q][k], +8 pad

    const int t = threadIdx.x;
    const int lane = t & 63;
    const int wave = t >> 6;
    const int lrow = lane & 15;
    const int lkq  = lane >> 4;
    const int bx = blockIdx.x;
    const int qtile = (bx & 1) ? (bx >> 1) : (15 - (bx >> 1));   // longest first
    const int bh = blockIdx.y;
    const int q0 = qtile * 128;

    const bf16_t* Qbh = Qw + (size_t)bh * SS * HD;
    const bf16_t* Kbh = Kw + (size_t)bh * SS * HD;
    const bf16_t* Vbh = Vtw + (size_t)bh * HD * SS;

    const int qb[2] = { q0 + wave * 16, q0 + 64 + wave * 16 };

    // Q fragments (B-operand layout: n=lane&15=q, k=quad*8+j), scale*log2e folded
    const float qscale = 0.08838834764831845f * 1.4426950408889634f;
    bf16x8 qf[2][4];
#pragma unroll
    for (int qs = 0; qs < 2; ++qs)
#pragma unroll
        for (int kc4 = 0; kc4 < 4; ++kc4) {
            qf[qs][kc4] = *(const bf16x8*)(Qbh + (size_t)(qb[qs] + lrow) * HD + kc4 * 32 + lkq * 8);
#pragma unroll
            for (int e = 0; e < 8; ++e) qf[qs][kc4][e] = (bf16_t)((float)qf[qs][kc4][e] * qscale);
        }

    floatx4 oacc[2][8];
#pragma unroll
    for (int qs = 0; qs < 2; ++qs)
#pragma unroll
        for (int i = 0; i < 8; ++i) oacc[qs][i] = (floatx4)0.0f;
    float m_i[2] = { -1e30f, -1e30f };
    float l_i[2] = { 0.0f, 0.0f };

    const int nch = 2 * qtile + 2;
    for (int kc = 0; kc < nch; ++kc) {
        __syncthreads();
        // stage K chunk [64][128]: 4 rows (256B each) per instr
#pragma unroll
        for (int p = 0; p < 4; ++p) {
            int row = wave * 16 + p * 4 + (lane >> 4);
            int gch = (lane & 15) ^ (row & 7);
            gl2lds16(Kbh + (size_t)(kc * 64 + row) * HD + gch * 8,
                     Ks + (wave * 16 + p * 4) * 128);
        }
        // stage V^T chunk [128][64]: 8 rows (128B each) per instr
#pragma unroll
        for (int p = 0; p < 4; ++p) {
            int row = wave * 32 + p * 8 + (lane >> 3);
            int gch = (lane & 7) ^ (row & 7);
            gl2lds16(Vbh + (size_t)row * SS + kc * 64 + gch * 8,
                     Vs + (wave * 32 + p * 8) * 64);
        }
        __syncthreads();

        const bool act0 = (kc * 64 <= qb[0] + 15);   // qs=1 active for all kc<nch

        // S^T[64k x 16q] both q-sets: one kf read feeds two MFMAs
        floatx4 sacc[2][4];
#pragma unroll
        for (int qs = 0; qs < 2; ++qs)
#pragma unroll
            for (int i = 0; i < 4; ++i) sacc[qs][i] = (floatx4)0.0f;
#pragma unroll
        for (int nf = 0; nf < 4; ++nf)
#pragma unroll
            for (int kc4 = 0; kc4 < 4; ++kc4) {
                bf16x8 kf = *(const bf16x8*)(Ks + (nf * 16 + lrow) * 128 +
                                             (((kc4 * 4 + lkq) ^ (lrow & 7)) * 8));
                if (act0)
                    sacc[0][nf] = __builtin_amdgcn_mfma_f32_16x16x32_bf16(kf, qf[0][kc4], sacc[0][nf], 0, 0, 0);
                sacc[1][nf] = __builtin_amdgcn_mfma_f32_16x16x32_bf16(kf, qf[1][kc4], sacc[1][nf], 0, 0, 0);
            }

        // softmax + P store per q-set; P A-fragments captured into regs
        bf16x8 pa[2][2];
#pragma unroll
        for (int qs = 0; qs < 2; ++qs) {
            const int qbase = qb[qs];                 // wave-uniform
            if (qs == 0 && !act0) continue;

            const int qg = qbase + lrow;
            float mx = m_i[qs];
            if (kc * 64 + 63 > qbase) {
                // diagonal chunk: causal mask + max
#pragma unroll
                for (int nf = 0; nf < 4; ++nf)
#pragma unroll
                    for (int r = 0; r < 4; ++r) {
                        int kg = kc * 64 + nf * 16 + lkq * 4 + r;
                        float sv = (kg > qg) ? -1e30f : sacc[qs][nf][r];
                        sacc[qs][nf][r] = sv;
                        mx = fmaxf(mx, sv);
                    }
            } else {
#pragma unroll
                for (int nf = 0; nf < 4; ++nf)
#pragma unroll
                    for (int r = 0; r < 4; ++r) mx = fmaxf(mx, sacc[qs][nf][r]);
            }
            mx = fmaxf(mx, __shfl_xor(mx, 16));
            mx = fmaxf(mx, __shfl_xor(mx, 32));
            float alpha = exp2f(m_i[qs] - mx);
            m_i[qs] = mx;

            float rs = 0.0f;
#pragma unroll
            for (int nf = 0; nf < 4; ++nf)
#pragma unroll
                for (int r = 0; r < 4; ++r) {
                    float pv = exp2f(sacc[qs][nf][r] - mx);
                    sacc[qs][nf][r] = pv;
                    rs += pv;
                }
            rs += __shfl_xor(rs, 16);
            rs += __shfl_xor(rs, 32);
            l_i[qs] = l_i[qs] * alpha + rs;

            // rescale O only if some lane's max moved (exact: exp2f(0)==1)
            if (__ballot(alpha < 1.0f)) {
                float av[4];
#pragma unroll
                for (int r = 0; r < 4; ++r) av[r] = __shfl(alpha, lkq * 4 + r);
#pragma unroll
                for (int nf8 = 0; nf8 < 8; ++nf8)
#pragma unroll
                    for (int r = 0; r < 4; ++r) oacc[qs][nf8][r] *= av[r];
            }

            // P store: 4 consecutive k per (nf) -> ds_write_b64 (per-wave)
#pragma unroll
            for (int nf = 0; nf < 4; ++nf) {
                bf16x4 pk;
#pragma unroll
                for (int r = 0; r < 4; ++r) pk[r] = (bf16_t)sacc[qs][nf][r];
                *(bf16x4*)(Ps[wave] + lrow * 72 + nf * 16 + lkq * 4) = pk;
            }
            // read back in A-operand layout before qs=1 overwrites the buffer
#pragma unroll
            for (int k2 = 0; k2 < 2; ++k2)
                pa[qs][k2] = *(const bf16x8*)(Ps[wave] + lrow * 72 + k2 * 32 + lkq * 8);
        }

        // PV both q-sets: one vf read feeds two MFMAs
#pragma unroll
        for (int nf8 = 0; nf8 < 8; ++nf8)
#pragma unroll
            for (int k2 = 0; k2 < 2; ++k2) {
                bf16x8 vf = *(const bf16x8*)(Vs + (nf8 * 16 + lrow) * 64 +
                                             (((k2 * 4 + lkq) ^ (lrow & 7)) * 8));
                if (act0)
                    oacc[0][nf8] = __builtin_amdgcn_mfma_f32_16x16x32_bf16(pa[0][k2], vf, oacc[0][nf8], 0, 0, 0);
                oacc[1][nf8] = __builtin_amdgcn_mfma_f32_16x16x32_bf16(pa[1][k2], vf, oacc[1][nf8], 0, 0, 0);
            }
    }

    // finalize: O /= l, write attn[b][s][h*128+d] (bf16)
    int bb = bh >> 4, h = bh & 15;
#pragma unroll
    for (int qs = 0; qs < 2; ++qs)
#pragma unroll
        for (int r = 0; r < 4; ++r) {
            float invl = 1.0f / __shfl(l_i[qs], lkq * 4 + r);
            int q = qb[qs] + lkq * 4 + r;
#pragma unroll
            for (int nf8 = 0; nf8 < 8; ++nf8)
                Attn[((size_t)bb * SS + q) * DD + h * HD + nf8 * 16 + lrow] =
                    (bf16_t)(oacc[qs][nf8][r] * invl);
        }
}

// ---------------------------------------------------------------------------
extern "C" void kernel_launch(void* const* d_in, const int* in_sizes, int n_in,
                              void* d_out, int out_size, void* d_ws, size_t ws_size,
                              hipStream_t stream) {
    const float* x  = (const float*)d_in[0];
    const float* Wq = (const float*)d_in[1];
    const float* Wk = (const float*)d_in[2];
    const float* Wv = (const float*)d_in[3];
    const float* Wo = (const float*)d_in[4];
    float* out = (float*)d_out;

    bf16_t* p = (bf16_t*)d_ws;
    bf16_t* Xb    = p; p += (size_t)BB * SS * DD;
    bf16_t* Wqkvt = p; p += (size_t)3 * DD * DD;
    bf16_t* Wot   = p; p += (size_t)DD * DD;
    bf16_t* Qw    = p; p += (size_t)BB * HH * SS * HD;
    bf16_t* Kw    = p; p += (size_t)BB * HH * SS * HD;
    bf16_t* Vtw   = p; p += (size_t)BB * HH * SS * HD;
    bf16_t* Attn  = p; p += (size_t)BB * SS * DD;
    // V natural layout lives in the Attn region (dead until flash writes it):
    bf16_t* Vw = Attn;

    cast_x_kernel<<<(BB * SS * DD / 4) / 256, 256, 0, stream>>>(x, Xb);

    dim3 tb(32, 8), tg(DD / 32, DD / 32);
    transpose_cast_kernel<<<tg, tb, 0, stream>>>(Wq, Wqkvt);
    transpose_cast_kernel<<<tg, tb, 0, stream>>>(Wk, Wqkvt + (size_t)DD * DD);
    transpose_cast_kernel<<<tg, tb, 0, stream>>>(Wv, Wqkvt + (size_t)2 * DD * DD);
    transpose_cast_kernel<<<tg, tb, 0, stream>>>(Wo, Wot);

    // QKV: [4096 x 2048] @ [2048 x 6144] -> Q/K/V (all natural [bh][s][d])
    gemm_bt_kernel<0><<<dim3(3 * DD / 128, BB * SS / 128), 256, 0, stream>>>(
        Xb, Wqkvt, nullptr, Qw, Kw, Vw, 3 * DD, DD);

    rope_kernel<<<(BB * HH * SS * 64) / 256, 256, 0, stream>>>(Qw, Kw);

    // V [bh][s][d] -> Vt [bh][d][s], coalesced LDS transpose
    vtrans_kernel<<<dim3(SS / 64, HD / 64, BB * HH), 256, 0, stream>>>(Vw, Vtw);

    flash_attn_kernel<<<dim3(SS / 128, BB * HH), 256, 0, stream>>>(Qw, Kw, Vtw, Attn);

    // out = attn @ Wo : [4096 x 2048] @ [2048 x 2048] -> fp32
    gemm_bt_kernel<1><<<dim3(DD / 128, BB * SS / 128), 256, 0, stream>>>(
        Attn, Wot, out, nullptr, nullptr, nullptr, DD, DD);
}